// Round 3
// baseline (940.044 us; speedup 1.0000x reference)
//
#include <hip/hip_runtime.h>

#define WS7    7
#define SHIFT3 3
#define NHEAD  6
#define CCH    192
#define HDIM   32
#define HH56   56
#define LTOK   (HH56*HH56)      // 3136
#define NWIN   64
#define NBATCH 32
#define NWTOT  (NBATCH*NWIN)    // 2048
#define LW     49
#define MTOK   (NWTOT*LW)       // 100352

typedef unsigned short u16;
typedef unsigned int   u32;
typedef __bf16 b16;
typedef b16   b16x8 __attribute__((ext_vector_type(8)));
typedef u16   u16x8 __attribute__((ext_vector_type(8)));
typedef float f32x4 __attribute__((ext_vector_type(4)));

__device__ __forceinline__ float b2f(u16 u) {
    u32 x = ((u32)u) << 16;
    return __builtin_bit_cast(float, x);
}
__device__ __forceinline__ u16 f2b(float f) {
    u32 x = __builtin_bit_cast(u32, f);
    u32 r = x + 0x7FFFu + ((x >> 16) & 1u);
    return (u16)(r >> 16);
}
__device__ __forceinline__ float gelu_exact(float x) {
    return 0.5f * x * (1.0f + erff(x * 0.7071067811865475f));
}

// token m (window-order) -> (b, l) image order (bijection)
__device__ __forceinline__ int map_token(int m, int &b) {
    int widx = m / LW, p = m - widx * LW;
    b = widx >> 6;
    int wloc = widx & 63;
    int wh = wloc >> 3, ww = wloc & 7;
    int i = p / WS7, j = p - i * WS7;
    int gh = wh * WS7 + i + SHIFT3; if (gh >= HH56) gh -= HH56;
    int gw = ww * WS7 + j + SHIFT3; if (gw >= HH56) gw -= HH56;
    return gh * HH56 + gw;
}

// ---- dtype probe: flag=1 if x is fp32 storage, 0 if bf16 storage
__global__ __launch_bounds__(256) void probe_kernel(const u16* __restrict__ x, int* flag) {
    __shared__ int ch, cz;
    if (threadIdx.x == 0) { ch = 0; cz = 0; }
    __syncthreads();
    int h = 0, z = 0;
    for (int i = threadIdx.x; i < 65536; i += 256) {
        u16 u = x[i];
        int e = (u >> 7) & 0xFF;
        h += (e >= 0xC0);
        z += (u == 0);
    }
    atomicAdd(&ch, h);
    atomicAdd(&cz, z);
    __syncthreads();
    if (threadIdx.x == 0) *flag = (ch > 1000 || cz > 8192) ? 1 : 0;
}

// ---- canonicalize a param tensor to bf16
__global__ __launch_bounds__(256) void canon_kernel(const int* __restrict__ flag,
                                                    const void* __restrict__ src,
                                                    u16* __restrict__ dst, int n) {
    int i = blockIdx.x * 256 + threadIdx.x;
    if (i >= n) return;
    if (*flag) dst[i] = f2b(((const float*)src)[i]);
    else       dst[i] = ((const u16*)src)[i];
}

// ---- LayerNorm. GATHER=1: src = d_in[0] (dtype per flag), rows via map_token.
//      GATHER=0: src = internal bf16, identity rows.
template<int GATHER>
__global__ __launch_bounds__(256) void ln_kernel(
    const void* __restrict__ src, const u16* __restrict__ w, const u16* __restrict__ bia,
    u16* __restrict__ dst, int m_base, const int* __restrict__ flag)
{
    int wave = threadIdx.x >> 6, lane = threadIdx.x & 63;
    int mloc = blockIdx.x * 4 + wave;
    size_t row;
    if (GATHER) { int b; int l = map_token(m_base + mloc, b); row = (size_t)b * LTOK + l; }
    else row = mloc;
    float v0, v1, v2;
    if (GATHER && *flag) {
        const float* xp = (const float*)src + row * CCH;
        v0 = xp[lane]; v1 = xp[lane + 64]; v2 = xp[lane + 128];
    } else {
        const u16* xp = (const u16*)src + row * CCH;
        v0 = b2f(xp[lane]); v1 = b2f(xp[lane + 64]); v2 = b2f(xp[lane + 128]);
    }
    float s = v0 + v1 + v2, sq = v0 * v0 + v1 * v1 + v2 * v2;
    for (int off = 32; off > 0; off >>= 1) {
        s  += __shfl_xor(s, off, 64);
        sq += __shfl_xor(sq, off, 64);
    }
    float mean = s * (1.f / 192.f);
    float var  = fmaxf(sq * (1.f / 192.f) - mean * mean, 0.f);
    float rstd = rsqrtf(var + 1e-5f);
    u16* op = dst + (size_t)mloc * CCH;
    op[lane]       = f2b((v0 - mean) * rstd * b2f(w[lane])       + b2f(bia[lane]));
    op[lane + 64]  = f2b((v1 - mean) * rstd * b2f(w[lane + 64])  + b2f(bia[lane + 64]));
    op[lane + 128] = f2b((v2 - mean) * rstd * b2f(w[lane + 128]) + b2f(bia[lane + 128]));
}

// ---- GEMM: D[m][n] = sum_k A[m][k]*Bm[n][k], bf16, fp32 acc, 64x64 tile.
// MODE 0: store bf16. MODE 1: +bias, scatter via map_token, X1 = Xin(flag dtype)+val.
// MODE 2: +bias, gelu -> bf16. MODE 3: +bias, gelu, +X1 -> Oout (flag dtype) at o_off.
template<int MODE>
__global__ __launch_bounds__(256) void gemm_bt_kernel(
    const u16* __restrict__ A, const u16* __restrict__ Bm, int K, int N,
    const u16* __restrict__ bias,
    u16* __restrict__ Cb,
    u16* __restrict__ X1,
    const void* __restrict__ Xin,
    void* __restrict__ Oout, size_t o_off, int m_base,
    const int* __restrict__ flag)
{
    __shared__ __align__(16) u16 As[64 * 32];
    __shared__ __align__(16) u16 Bs[64 * 32];
    int isf = *flag;
    int tid = threadIdx.x;
    int m0 = blockIdx.x * 64, n0 = blockIdx.y * 64;
    int wave = tid >> 6, lane = tid & 63;
    int wm = wave >> 1, wn = wave & 1;
    int quad = lane >> 4, mr = lane & 15;
    f32x4 acc00 = {}, acc01 = {}, acc10 = {}, acc11 = {};

    int lr = tid >> 2;
    int lc = (tid & 3) * 8;
    const u16* ga = A  + (size_t)(m0 + lr) * K + lc;
    const u16* gb = Bm + (size_t)(n0 + lr) * K + lc;
    u16* sa = &As[lr * 32 + lc];
    u16* sb = &Bs[lr * 32 + lc];
    const u16* pa0 = &As[(wm * 32 + mr) * 32 + quad * 8];
    const u16* pb0 = &Bs[(wn * 32 + mr) * 32 + quad * 8];

    for (int k0 = 0; k0 < K; k0 += 32) {
        *(uint4*)sa = *(const uint4*)(ga + k0);
        *(uint4*)sb = *(const uint4*)(gb + k0);
        __syncthreads();
        b16x8 a0 = __builtin_bit_cast(b16x8, *(const u16x8*)pa0);
        b16x8 a1 = __builtin_bit_cast(b16x8, *(const u16x8*)(pa0 + 16 * 32));
        b16x8 b0 = __builtin_bit_cast(b16x8, *(const u16x8*)pb0);
        b16x8 b1 = __builtin_bit_cast(b16x8, *(const u16x8*)(pb0 + 16 * 32));
        acc00 = __builtin_amdgcn_mfma_f32_16x16x32_bf16(a0, b0, acc00, 0, 0, 0);
        acc01 = __builtin_amdgcn_mfma_f32_16x16x32_bf16(a0, b1, acc01, 0, 0, 0);
        acc10 = __builtin_amdgcn_mfma_f32_16x16x32_bf16(a1, b0, acc10, 0, 0, 0);
        acc11 = __builtin_amdgcn_mfma_f32_16x16x32_bf16(a1, b1, acc11, 0, 0, 0);
        __syncthreads();
    }

    f32x4 accs[2][2] = {{acc00, acc01}, {acc10, acc11}};
    for (int sm = 0; sm < 2; sm++) {
        for (int sn = 0; sn < 2; sn++) {
            f32x4 v = accs[sm][sn];
            int nn = n0 + wn * 32 + sn * 16 + mr;
            int mb = m0 + wm * 32 + sm * 16 + quad * 4;
            for (int r = 0; r < 4; r++) {
                int mm = mb + r;
                float val = v[r];
                if (MODE == 0) {
                    Cb[(size_t)mm * N + nn] = f2b(val);
                } else if (MODE == 1) {
                    val += b2f(bias[nn]);
                    int b; int l = map_token(m_base + mm, b);
                    size_t idx = ((size_t)b * LTOK + l) * CCH + nn;
                    float xi = isf ? ((const float*)Xin)[idx] : b2f(((const u16*)Xin)[idx]);
                    X1[idx] = f2b(xi + val);
                } else if (MODE == 2) {
                    val = gelu_exact(val + b2f(bias[nn]));
                    Cb[(size_t)mm * N + nn] = f2b(val);
                } else {
                    val = gelu_exact(val + b2f(bias[nn]));
                    size_t idx = (size_t)mm * CCH + nn;
                    float r2 = val + b2f(X1[idx]);
                    if (isf) ((float*)Oout)[o_off + idx] = r2;
                    else     ((u16*)Oout)[o_off + idx]  = f2b(r2);
                }
            }
        }
    }
}

// ---- fused attention per (window, head); qkv/aout chunk-local (chunk multiple of 64 windows)
__global__ __launch_bounds__(256) void attn_kernel(
    const u16* __restrict__ qkv, const u16* __restrict__ rel_bias,
    u16* __restrict__ aout)
{
    __shared__ float qs[LW][HDIM + 1];
    __shared__ float ks[LW][HDIM + 1];
    __shared__ float vs[LW][HDIM + 1];
    __shared__ float Ss[LW][LW + 3];
    int blk = blockIdx.x;
    int widx = blk / NHEAD, head = blk - widx * NHEAD;
    int wloc = widx & 63;
    int wh = wloc >> 3, ww = wloc & 7;
    int tid = threadIdx.x;
    const u16* base = qkv + (size_t)widx * LW * 576 + head * HDIM;
    for (int idx = tid; idx < LW * HDIM; idx += 256) {
        int p = idx >> 5, d = idx & 31;
        const u16* bp = base + (size_t)p * 576 + d;
        qs[p][d] = b2f(bp[0]);
        ks[p][d] = b2f(bp[192]);
        vs[p][d] = b2f(bp[384]);
    }
    __syncthreads();
    for (int idx = tid; idx < LW * LW; idx += 256) {
        int i = idx / LW, j = idx - i * LW;
        float s = 0.f;
        #pragma unroll
        for (int d = 0; d < HDIM; d++) s += qs[i][d] * ks[j][d];
        int ih = i / WS7, iw = i - ih * WS7;
        int jh = j / WS7, jw = j - jh * WS7;
        int ri = (wh == 7 ? (ih < 4 ? 1 : 2) : 0) * 3 + (ww == 7 ? (iw < 4 ? 1 : 2) : 0);
        int rj = (wh == 7 ? (jh < 4 ? 1 : 2) : 0) * 3 + (ww == 7 ? (jw < 4 ? 1 : 2) : 0);
        float out;
        if (ri != rj) {
            out = -100.0f;
        } else {
            int rc = (ih - jh + 6) * 13 + (iw - jw + 6);
            out = s * 13.856406460551018f + b2f(rel_bias[rc * NHEAD + head]);
        }
        Ss[i][j] = out;
    }
    __syncthreads();
    if (tid < LW) {
        int i = tid;
        float mx = -1e30f;
        for (int j = 0; j < LW; j++) mx = fmaxf(mx, Ss[i][j]);
        float sum = 0.f;
        for (int j = 0; j < LW; j++) { float e = expf(Ss[i][j] - mx); Ss[i][j] = e; sum += e; }
        float inv = 1.f / sum;
        for (int j = 0; j < LW; j++) Ss[i][j] *= inv;
    }
    __syncthreads();
    for (int idx = tid; idx < LW * HDIM; idx += 256) {
        int i = idx >> 5, d = idx & 31;
        float o = 0.f;
        #pragma unroll
        for (int j = 0; j < LW; j++) o += Ss[i][j] * vs[j][d];
        aout[((size_t)widx * LW + i) * CCH + head * HDIM + d] = f2b(o);
    }
}

extern "C" void kernel_launch(void* const* d_in, const int* in_sizes, int n_in,
                              void* d_out, int out_size, void* d_ws, size_t ws_size,
                              hipStream_t stream)
{
    const void* x_in = d_in[0];
    char* ws = (char*)d_ws;
    int* flag = (int*)ws;

    // bf16 param arena
    u16* qkvw_c = (u16*)(ws + 64);        // 110592
    u16* projw_c = (u16*)(ws + 221248);   // 36864
    u16* fc1w_c = (u16*)(ws + 294976);    // 147456
    u16* fc2w_c = (u16*)(ws + 589888);    // 147456
    u16* n1w_c  = (u16*)(ws + 884800);
    u16* n1b_c  = (u16*)(ws + 885184);
    u16* n2w_c  = (u16*)(ws + 885568);
    u16* n2b_c  = (u16*)(ws + 885952);
    u16* projb_c= (u16*)(ws + 886336);
    u16* fc1b_c = (u16*)(ws + 886720);
    u16* fc2b_c = (u16*)(ws + 888256);
    u16* relb_c = (u16*)(ws + 888640);

    const size_t P0 = 1u << 20;
    u16* x1   = (u16*)(ws + P0);                         // 38,535,168 B
    u16* winq = (u16*)(ws + P0 + 38535168);              //  9,633,792 B
    u16* qkvq = (u16*)(ws + P0 + 38535168 + 9633792);    // 28,901,376 B  (peak ~78.1 MB)
    u16* xnq  = winq;                                    //  4,816,896 B (stage B, over dead winq)
    u16* h1q  = (u16*)(ws + P0 + 38535168 + 4816896);    // 19,267,584 B

    probe_kernel<<<1, 256, 0, stream>>>((const u16*)x_in, flag);

    auto canon = [&](int src_idx, u16* dst, int n) {
        canon_kernel<<<(n + 255) / 256, 256, 0, stream>>>(flag, d_in[src_idx], dst, n);
    };
    canon(7,  qkvw_c, 110592);
    canon(9,  projw_c, 36864);
    canon(13, fc1w_c, 147456);
    canon(15, fc2w_c, 147456);
    canon(5,  n1w_c, 192);
    canon(6,  n1b_c, 192);
    canon(11, n2w_c, 192);
    canon(12, n2b_c, 192);
    canon(10, projb_c, 192);
    canon(14, fc1b_c, 768);
    canon(16, fc2b_c, 192);
    canon(8,  relb_c, 1014);

    const int M4 = MTOK / 4;   // 25088
    const int M8 = MTOK / 8;   // 12544

    for (int q = 0; q < 4; q++) {
        int mb = q * M4;
        ln_kernel<1><<<M4 / 4, 256, 0, stream>>>(x_in, n1w_c, n1b_c, winq, mb, flag);
        gemm_bt_kernel<0><<<dim3(M4 / 64, 9), 256, 0, stream>>>(
            winq, qkvw_c, 192, 576, nullptr, qkvq, nullptr, nullptr, nullptr, 0, 0, flag);
        attn_kernel<<<(NWTOT / 4) * NHEAD, 256, 0, stream>>>(qkvq, relb_c, winq);
        gemm_bt_kernel<1><<<dim3(M4 / 64, 3), 256, 0, stream>>>(
            winq, projw_c, 192, 192, projb_c, nullptr, x1, x_in, nullptr, 0, mb, flag);
    }

    for (int e = 0; e < 8; e++) {
        size_t off = (size_t)e * M8 * CCH;
        ln_kernel<0><<<M8 / 4, 256, 0, stream>>>(x1 + off, n2w_c, n2b_c, xnq, 0, flag);
        gemm_bt_kernel<2><<<dim3(M8 / 64, 12), 256, 0, stream>>>(
            xnq, fc1w_c, 192, 768, fc1b_c, h1q, nullptr, nullptr, nullptr, 0, 0, flag);
        gemm_bt_kernel<3><<<dim3(M8 / 64, 3), 256, 0, stream>>>(
            h1q, fc2w_c, 768, 192, fc2b_c, nullptr, x1 + off, nullptr, d_out, off, 0, flag);
    }
}

// Round 4
// 820.476 us; speedup vs baseline: 1.1457x; 1.1457x over previous
//
#include <hip/hip_runtime.h>

#define WS7    7
#define SHIFT3 3
#define NHEAD  6
#define CCH    192
#define HDIM   32
#define HH56   56
#define LTOK   (HH56*HH56)      // 3136
#define NWIN   64
#define NBATCH 32
#define NWTOT  (NBATCH*NWIN)    // 2048
#define LW     49
#define MTOK   (NWTOT*LW)       // 100352

typedef unsigned short u16;
typedef unsigned int   u32;
typedef __bf16 b16;
typedef b16   b16x8 __attribute__((ext_vector_type(8)));
typedef u16   u16x8 __attribute__((ext_vector_type(8)));
typedef float f32x4 __attribute__((ext_vector_type(4)));

__device__ __forceinline__ float b2f(u16 u) {
    u32 x = ((u32)u) << 16;
    return __builtin_bit_cast(float, x);
}
__device__ __forceinline__ u16 f2b(float f) {
    u32 x = __builtin_bit_cast(u32, f);
    u32 r = x + 0x7FFFu + ((x >> 16) & 1u);
    return (u16)(r >> 16);
}
__device__ __forceinline__ float gelu_exact(float x) {
    return 0.5f * x * (1.0f + erff(x * 0.7071067811865475f));
}

// token m (window-order) -> (b, l) image order (bijection)
__device__ __forceinline__ int map_token(int m, int &b) {
    int widx = m / LW, p = m - widx * LW;
    b = widx >> 6;
    int wloc = widx & 63;
    int wh = wloc >> 3, ww = wloc & 7;
    int i = p / WS7, j = p - i * WS7;
    int gh = wh * WS7 + i + SHIFT3; if (gh >= HH56) gh -= HH56;
    int gw = ww * WS7 + j + SHIFT3; if (gw >= HH56) gw -= HH56;
    return gh * HH56 + gw;
}

// ---- dtype probe: flag=1 if x is fp32 storage, 0 if bf16 storage
__global__ __launch_bounds__(256) void probe_kernel(const u16* __restrict__ x, int* flag) {
    __shared__ int ch, cz;
    if (threadIdx.x == 0) { ch = 0; cz = 0; }
    __syncthreads();
    int h = 0, z = 0;
    for (int i = threadIdx.x; i < 65536; i += 256) {
        u16 u = x[i];
        int e = (u >> 7) & 0xFF;
        h += (e >= 0xC0);
        z += (u == 0);
    }
    atomicAdd(&ch, h);
    atomicAdd(&cz, z);
    __syncthreads();
    if (threadIdx.x == 0) *flag = (ch > 1000 || cz > 8192) ? 1 : 0;
}

// ---- canonicalize a param tensor to bf16
__global__ __launch_bounds__(256) void canon_kernel(const int* __restrict__ flag,
                                                    const void* __restrict__ src,
                                                    u16* __restrict__ dst, int n) {
    int i = blockIdx.x * 256 + threadIdx.x;
    if (i >= n) return;
    if (*flag) dst[i] = f2b(((const float*)src)[i]);
    else       dst[i] = ((const u16*)src)[i];
}

// ---- LayerNorm. GATHER=1: src = d_in[0] (dtype per flag), rows via map_token.
template<int GATHER>
__global__ __launch_bounds__(256) void ln_kernel(
    const void* __restrict__ src, const u16* __restrict__ w, const u16* __restrict__ bia,
    u16* __restrict__ dst, int m_base, const int* __restrict__ flag)
{
    int wave = threadIdx.x >> 6, lane = threadIdx.x & 63;
    int mloc = blockIdx.x * 4 + wave;
    size_t row;
    if (GATHER) { int b; int l = map_token(m_base + mloc, b); row = (size_t)b * LTOK + l; }
    else row = mloc;
    float v0, v1, v2;
    if (GATHER && *flag) {
        const float* xp = (const float*)src + row * CCH;
        v0 = xp[lane]; v1 = xp[lane + 64]; v2 = xp[lane + 128];
    } else {
        const u16* xp = (const u16*)src + row * CCH;
        v0 = b2f(xp[lane]); v1 = b2f(xp[lane + 64]); v2 = b2f(xp[lane + 128]);
    }
    float s = v0 + v1 + v2, sq = v0 * v0 + v1 * v1 + v2 * v2;
    for (int off = 32; off > 0; off >>= 1) {
        s  += __shfl_xor(s, off, 64);
        sq += __shfl_xor(sq, off, 64);
    }
    float mean = s * (1.f / 192.f);
    float var  = fmaxf(sq * (1.f / 192.f) - mean * mean, 0.f);
    float rstd = rsqrtf(var + 1e-5f);
    u16* op = dst + (size_t)mloc * CCH;
    op[lane]       = f2b((v0 - mean) * rstd * b2f(w[lane])       + b2f(bia[lane]));
    op[lane + 64]  = f2b((v1 - mean) * rstd * b2f(w[lane + 64])  + b2f(bia[lane + 64]));
    op[lane + 128] = f2b((v2 - mean) * rstd * b2f(w[lane + 128]) + b2f(bia[lane + 128]));
}

// ---- GEMM: D[m][n] = sum_k A[m][k]*Bm[n][k], bf16, fp32 acc, 64x64 tile.
template<int MODE>
__global__ __launch_bounds__(256) void gemm_bt_kernel(
    const u16* __restrict__ A, const u16* __restrict__ Bm, int K, int N,
    const u16* __restrict__ bias,
    u16* __restrict__ Cb,
    u16* __restrict__ X1,
    const void* __restrict__ Xin,
    void* __restrict__ Oout, size_t o_off, int m_base,
    const int* __restrict__ flag)
{
    __shared__ __align__(16) u16 As[64 * 32];
    __shared__ __align__(16) u16 Bs[64 * 32];
    int isf = *flag;
    int tid = threadIdx.x;
    int m0 = blockIdx.x * 64, n0 = blockIdx.y * 64;
    int wave = tid >> 6, lane = tid & 63;
    int wm = wave >> 1, wn = wave & 1;
    int quad = lane >> 4, mr = lane & 15;
    f32x4 acc00 = {}, acc01 = {}, acc10 = {}, acc11 = {};

    int lr = tid >> 2;
    int lc = (tid & 3) * 8;
    const u16* ga = A  + (size_t)(m0 + lr) * K + lc;
    const u16* gb = Bm + (size_t)(n0 + lr) * K + lc;
    u16* sa = &As[lr * 32 + lc];
    u16* sb = &Bs[lr * 32 + lc];
    const u16* pa0 = &As[(wm * 32 + mr) * 32 + quad * 8];
    const u16* pb0 = &Bs[(wn * 32 + mr) * 32 + quad * 8];

    for (int k0 = 0; k0 < K; k0 += 32) {
        *(uint4*)sa = *(const uint4*)(ga + k0);
        *(uint4*)sb = *(const uint4*)(gb + k0);
        __syncthreads();
        b16x8 a0 = __builtin_bit_cast(b16x8, *(const u16x8*)pa0);
        b16x8 a1 = __builtin_bit_cast(b16x8, *(const u16x8*)(pa0 + 16 * 32));
        b16x8 b0 = __builtin_bit_cast(b16x8, *(const u16x8*)pb0);
        b16x8 b1 = __builtin_bit_cast(b16x8, *(const u16x8*)(pb0 + 16 * 32));
        acc00 = __builtin_amdgcn_mfma_f32_16x16x32_bf16(a0, b0, acc00, 0, 0, 0);
        acc01 = __builtin_amdgcn_mfma_f32_16x16x32_bf16(a0, b1, acc01, 0, 0, 0);
        acc10 = __builtin_amdgcn_mfma_f32_16x16x32_bf16(a1, b0, acc10, 0, 0, 0);
        acc11 = __builtin_amdgcn_mfma_f32_16x16x32_bf16(a1, b1, acc11, 0, 0, 0);
        __syncthreads();
    }

    f32x4 accs[2][2] = {{acc00, acc01}, {acc10, acc11}};
    for (int sm = 0; sm < 2; sm++) {
        for (int sn = 0; sn < 2; sn++) {
            f32x4 v = accs[sm][sn];
            int nn = n0 + wn * 32 + sn * 16 + mr;
            int mb = m0 + wm * 32 + sm * 16 + quad * 4;
            for (int r = 0; r < 4; r++) {
                int mm = mb + r;
                float val = v[r];
                if (MODE == 0) {
                    Cb[(size_t)mm * N + nn] = f2b(val);
                } else if (MODE == 1) {
                    val += b2f(bias[nn]);
                    int b; int l = map_token(m_base + mm, b);
                    size_t idx = ((size_t)b * LTOK + l) * CCH + nn;
                    float xi = isf ? ((const float*)Xin)[idx] : b2f(((const u16*)Xin)[idx]);
                    X1[idx] = f2b(xi + val);
                } else if (MODE == 2) {
                    val = gelu_exact(val + b2f(bias[nn]));
                    Cb[(size_t)mm * N + nn] = f2b(val);
                } else {
                    val = gelu_exact(val + b2f(bias[nn]));
                    size_t idx = (size_t)mm * CCH + nn;
                    float r2 = val + b2f(X1[idx]);
                    if (isf) ((float*)Oout)[o_off + idx] = r2;
                    else     ((u16*)Oout)[o_off + idx]  = f2b(r2);
                }
            }
        }
    }
}

// ---- MFMA attention: 1 block = 1 (window, head); 4 waves = 4 row-tiles of 64x64 S.
// Q,K row-major [tok][d]; V transposed [d][tok] (pad cols zeroed); P via LDS
// (each wave reads only its own rows -> no barrier between S and PV phases).
__global__ __launch_bounds__(256) void attn_kernel(
    const u16* __restrict__ qkv, const u16* __restrict__ rel_bias,
    u16* __restrict__ aout)
{
    __shared__ __align__(16) u16 qs[64 * 32];
    __shared__ __align__(16) u16 ks[64 * 32];
    __shared__ __align__(16) u16 vsT[32 * 64];
    __shared__ __align__(16) u16 ps[64 * 64];
    __shared__ float bias_s[169];
    int blk = blockIdx.x;
    int widx = blk / NHEAD, head = blk - widx * NHEAD;
    int wloc = widx & 63;
    int wh = wloc >> 3, ww = wloc & 7;
    int tid = threadIdx.x;
    const u16* base = qkv + (size_t)widx * LW * 576 + head * HDIM;

    if (tid < 196) {
        int i = tid >> 2, c = (tid & 3) * 8;
        *(uint4*)&qs[i * 32 + c] = *(const uint4*)(base + (size_t)i * 576 + c);
        *(uint4*)&ks[i * 32 + c] = *(const uint4*)(base + (size_t)i * 576 + 192 + c);
    }
    for (int idx = tid; idx < 32 * 64; idx += 256) {
        int d = idx >> 6, j = idx & 63;
        vsT[d * 64 + j] = (j < LW) ? base[(size_t)j * 576 + 384 + d] : (u16)0;
    }
    if (tid < 169) bias_s[tid] = b2f(rel_bias[tid * NHEAD + head]);
    __syncthreads();

    int wave = tid >> 6, lane = tid & 63;
    int quad = lane >> 4, c = lane & 15;

    // ---- S = Q @ K^T  (row-tile mt = wave)
    b16x8 aq = __builtin_bit_cast(b16x8, *(const u16x8*)&qs[(wave * 16 + c) * 32 + quad * 8]);
    f32x4 sacc[4];
    #pragma unroll
    for (int nt = 0; nt < 4; nt++) {
        b16x8 bk = __builtin_bit_cast(b16x8, *(const u16x8*)&ks[(nt * 16 + c) * 32 + quad * 8]);
        f32x4 z = {};
        sacc[nt] = __builtin_amdgcn_mfma_f32_16x16x32_bf16(aq, bk, z, 0, 0, 0);
    }

    // ---- epilogue: scale + bias + mask, per-element (row i, col j)
    const float SCALE = 13.856406460551018f;
    float val[4][4];
    int rbase = wave * 16 + quad * 4;
    #pragma unroll
    for (int r = 0; r < 4; r++) {
        int i = rbase + r;
        int ih = i / WS7, iw = i - ih * WS7;
        int ri = (wh == 7 ? (ih < 4 ? 1 : 2) : 0) * 3 + (ww == 7 ? (iw < 4 ? 1 : 2) : 0);
        #pragma unroll
        for (int nt = 0; nt < 4; nt++) {
            int j = nt * 16 + c;
            float v;
            if (i >= LW) v = 0.f;
            else if (j >= LW) v = -1e30f;
            else {
                int jh = j / WS7, jw = j - jh * WS7;
                int rj = (wh == 7 ? (jh < 4 ? 1 : 2) : 0) * 3 + (ww == 7 ? (jw < 4 ? 1 : 2) : 0);
                if (ri != rj) v = -100.0f;
                else v = fmaf(sacc[nt][r], SCALE, bias_s[(ih - jh + 6) * 13 + (iw - jw + 6)]);
            }
            val[r][nt] = v;
        }
    }

    // ---- softmax over each row (16 lanes of same quad hold the row)
    #pragma unroll
    for (int r = 0; r < 4; r++) {
        float mx = fmaxf(fmaxf(val[r][0], val[r][1]), fmaxf(val[r][2], val[r][3]));
        for (int d = 1; d < 16; d <<= 1) mx = fmaxf(mx, __shfl_xor(mx, d, 64));
        float sum = 0.f;
        #pragma unroll
        for (int nt = 0; nt < 4; nt++) { float e = expf(val[r][nt] - mx); val[r][nt] = e; sum += e; }
        for (int d = 1; d < 16; d <<= 1) sum += __shfl_xor(sum, d, 64);
        float inv = 1.f / sum;
        int i = rbase + r;
        #pragma unroll
        for (int nt = 0; nt < 4; nt++)
            ps[i * 64 + nt * 16 + c] = f2b(val[r][nt] * inv);
    }

    // ---- O = P @ V   (own rows only; ds_write->ds_read ordered by lgkmcnt)
    f32x4 oacc[2] = {{}, {}};
    #pragma unroll
    for (int kh = 0; kh < 2; kh++) {
        b16x8 ap = __builtin_bit_cast(b16x8, *(const u16x8*)&ps[(wave * 16 + c) * 64 + kh * 32 + quad * 8]);
        #pragma unroll
        for (int nt = 0; nt < 2; nt++) {
            b16x8 bv = __builtin_bit_cast(b16x8, *(const u16x8*)&vsT[(nt * 16 + c) * 64 + kh * 32 + quad * 8]);
            oacc[nt] = __builtin_amdgcn_mfma_f32_16x16x32_bf16(ap, bv, oacc[nt], 0, 0, 0);
        }
    }
    #pragma unroll
    for (int nt = 0; nt < 2; nt++) {
        #pragma unroll
        for (int r = 0; r < 4; r++) {
            int i = rbase + r;
            if (i < LW)
                aout[((size_t)widx * LW + i) * CCH + head * HDIM + nt * 16 + c] = f2b(oacc[nt][r]);
        }
    }
}

extern "C" void kernel_launch(void* const* d_in, const int* in_sizes, int n_in,
                              void* d_out, int out_size, void* d_ws, size_t ws_size,
                              hipStream_t stream)
{
    const void* x_in = d_in[0];
    char* ws = (char*)d_ws;
    int* flag = (int*)ws;

    u16* qkvw_c = (u16*)(ws + 64);
    u16* projw_c = (u16*)(ws + 221248);
    u16* fc1w_c = (u16*)(ws + 294976);
    u16* fc2w_c = (u16*)(ws + 589888);
    u16* n1w_c  = (u16*)(ws + 884800);
    u16* n1b_c  = (u16*)(ws + 885184);
    u16* n2w_c  = (u16*)(ws + 885568);
    u16* n2b_c  = (u16*)(ws + 885952);
    u16* projb_c= (u16*)(ws + 886336);
    u16* fc1b_c = (u16*)(ws + 886720);
    u16* fc2b_c = (u16*)(ws + 888256);
    u16* relb_c = (u16*)(ws + 888640);

    const size_t P0 = 1u << 20;
    u16* x1   = (u16*)(ws + P0);
    u16* winq = (u16*)(ws + P0 + 38535168);
    u16* qkvq = (u16*)(ws + P0 + 38535168 + 9633792);
    u16* xnq  = winq;
    u16* h1q  = (u16*)(ws + P0 + 38535168 + 4816896);

    probe_kernel<<<1, 256, 0, stream>>>((const u16*)x_in, flag);

    auto canon = [&](int src_idx, u16* dst, int n) {
        canon_kernel<<<(n + 255) / 256, 256, 0, stream>>>(flag, d_in[src_idx], dst, n);
    };
    canon(7,  qkvw_c, 110592);
    canon(9,  projw_c, 36864);
    canon(13, fc1w_c, 147456);
    canon(15, fc2w_c, 147456);
    canon(5,  n1w_c, 192);
    canon(6,  n1b_c, 192);
    canon(11, n2w_c, 192);
    canon(12, n2b_c, 192);
    canon(10, projb_c, 192);
    canon(14, fc1b_c, 768);
    canon(16, fc2b_c, 192);
    canon(8,  relb_c, 1014);

    const int M4 = MTOK / 4;   // 25088
    const int M8 = MTOK / 8;   // 12544

    for (int q = 0; q < 4; q++) {
        int mb = q * M4;
        ln_kernel<1><<<M4 / 4, 256, 0, stream>>>(x_in, n1w_c, n1b_c, winq, mb, flag);
        gemm_bt_kernel<0><<<dim3(M4 / 64, 9), 256, 0, stream>>>(
            winq, qkvw_c, 192, 576, nullptr, qkvq, nullptr, nullptr, nullptr, 0, 0, flag);
        attn_kernel<<<(NWTOT / 4) * NHEAD, 256, 0, stream>>>(qkvq, relb_c, winq);
        gemm_bt_kernel<1><<<dim3(M4 / 64, 3), 256, 0, stream>>>(
            winq, projw_c, 192, 192, projb_c, nullptr, x1, x_in, nullptr, 0, mb, flag);
    }

    for (int e = 0; e < 8; e++) {
        size_t off = (size_t)e * M8 * CCH;
        ln_kernel<0><<<M8 / 4, 256, 0, stream>>>(x1 + off, n2w_c, n2b_c, xnq, 0, flag);
        gemm_bt_kernel<2><<<dim3(M8 / 64, 12), 256, 0, stream>>>(
            xnq, fc1w_c, 192, 768, fc1b_c, h1q, nullptr, nullptr, nullptr, 0, 0, flag);
        gemm_bt_kernel<3><<<dim3(M8 / 64, 3), 256, 0, stream>>>(
            h1q, fc2w_c, 768, 192, fc2b_c, nullptr, x1 + off, nullptr, d_out, off, 0, flag);
    }
}